// Round 3
// baseline (2284.308 us; speedup 1.0000x reference)
//
#include <hip/hip_runtime.h>

#define L_SEQ 512
#define NB    64
#define DDIM  512
#define HHALF 256
#define GG    1024   // 4*HALF

using f32x4  = __attribute__((ext_vector_type(4))) float;
using bf16x8 = __attribute__((ext_vector_type(8))) short;
using f16x8  = __attribute__((ext_vector_type(8))) _Float16;

__device__ __forceinline__ unsigned short f2bf(float f) {
    unsigned u = __float_as_uint(f);
    u += 0x7fffu + ((u >> 16) & 1u);          // round-to-nearest-even
    return (unsigned short)(u >> 16);
}
__device__ __forceinline__ float fsigmoid(float x) {
    return 1.0f / (1.0f + __expf(-x));
}
__device__ __forceinline__ float ftanh(float x) {
    return 1.0f - 2.0f / (__expf(2.0f * x) + 1.0f);
}

// --- device-coherent (memory-side L3) access helpers -----------------------
// sc0|sc1 on gfx950: bypass L1 + (non-cross-coherent) L2, access the
// device-coherent point. Used for all cross-block-shared data so that NO
// buffer_wbl2 / buffer_inv cache maintenance is ever required.
__device__ __forceinline__ void st_short_wt(unsigned short* p, unsigned int v) {
    asm volatile("global_store_short %0, %1, off sc0 sc1" :: "v"(p), "v"(v) : "memory");
}
__device__ __forceinline__ void st_dword_wt(unsigned int* p, unsigned int v) {
    asm volatile("global_store_dword %0, %1, off sc0 sc1" :: "v"(p), "v"(v) : "memory");
}

// ---------------------------------------------------------------------------
// Phase 1: xwb[dir][t][b][g] (fp16) = x[t][b][:] . W_ih[g][:] + b_ih[g] + b_hh[g]
// f16 MFMA GEMM, M=32768 (t*64+b), N=1024 (g), K=512, fp32 accumulate.
// No LDS: fragments loaded straight from global with the verified lane layout:
//   A frag : lane l holds A[row = l&15][k = (l>>4)*8 + j]   (8 f16, 4 VGPRs)
//   B frag : lane l holds B[k = (l>>4)*8 + j][col = l&15]  == W[col][k]
//   C/D    : lane l, reg r -> row = (l>>4)*4 + r, col = l&15
// Block = 256 thr = 4 waves; tile 64(M) x 256(N); wave w owns cols w*64..+63.
// Block (0,0,0) zero-inits Hbuf + flags with WRITE-THROUGH stores (sc0 sc1)
// so the zeros are at the coherent point where lstm_recur's sc-flagged
// reads will look — plain stores would leave them dirty in one XCD's L2.
// ---------------------------------------------------------------------------
__global__ __launch_bounds__(256) void gemm_xwb(
    const float* __restrict__ x,
    const float* __restrict__ Wf, const float* __restrict__ Wb,
    const float* __restrict__ bihf, const float* __restrict__ bhhf,
    const float* __restrict__ bihb, const float* __restrict__ bhhb,
    _Float16* __restrict__ xwb,
    unsigned int* __restrict__ zero_base, int zero_words)
{
    const int dir = blockIdx.z;
    const float* __restrict__ W   = dir ? Wb   : Wf;
    const float* __restrict__ bih = dir ? bihb : bihf;
    const float* __restrict__ bhh = dir ? bhhb : bhhf;

    if (blockIdx.x == 0 && blockIdx.y == 0 && blockIdx.z == 0) {
        for (int i = threadIdx.x; i < zero_words; i += 256)
            st_dword_wt(zero_base + i, 0u);
    }

    const int tid = threadIdx.x;
    const int w   = tid >> 6;                  // wave -> col group
    const int l   = tid & 63;
    const int q   = l >> 4;                    // k-subchunk / acc row group
    const int c   = l & 15;                    // frag row (A) / frag col (B,D)

    const int m0 = blockIdx.y * 64;            // 512 m-blocks
    const int n0 = blockIdx.x * 256 + w * 64;  // 4 n-blocks x 4 waves

    const float* xa = x + (size_t)(m0 + c) * DDIM + q * 8;
    const float* wa = W + (size_t)(n0 + c) * DDIM + q * 8;

    f32x4 acc[4][4];
#pragma unroll
    for (int rb = 0; rb < 4; ++rb)
#pragma unroll
        for (int nb = 0; nb < 4; ++nb) {
            f32x4 z; z[0] = 0.f; z[1] = 0.f; z[2] = 0.f; z[3] = 0.f;
            acc[rb][nb] = z;
        }

#pragma unroll 2
    for (int k0 = 0; k0 < DDIM; k0 += 32) {
        f16x8 afrag[4], bfrag[4];
#pragma unroll
        for (int rb = 0; rb < 4; ++rb) {
            const float4* p = (const float4*)(xa + (size_t)rb * 16 * DDIM + k0);
            float4 u0 = p[0], u1 = p[1];
            f16x8 v;
            v[0] = (_Float16)u0.x; v[1] = (_Float16)u0.y;
            v[2] = (_Float16)u0.z; v[3] = (_Float16)u0.w;
            v[4] = (_Float16)u1.x; v[5] = (_Float16)u1.y;
            v[6] = (_Float16)u1.z; v[7] = (_Float16)u1.w;
            afrag[rb] = v;
        }
#pragma unroll
        for (int nb = 0; nb < 4; ++nb) {
            const float4* p = (const float4*)(wa + (size_t)nb * 16 * DDIM + k0);
            float4 u0 = p[0], u1 = p[1];
            f16x8 v;
            v[0] = (_Float16)u0.x; v[1] = (_Float16)u0.y;
            v[2] = (_Float16)u0.z; v[3] = (_Float16)u0.w;
            v[4] = (_Float16)u1.x; v[5] = (_Float16)u1.y;
            v[6] = (_Float16)u1.z; v[7] = (_Float16)u1.w;
            bfrag[nb] = v;
        }
#pragma unroll
        for (int rb = 0; rb < 4; ++rb)
#pragma unroll
            for (int nb = 0; nb < 4; ++nb)
                acc[rb][nb] = __builtin_amdgcn_mfma_f32_16x16x32_f16(
                    afrag[rb], bfrag[nb], acc[rb][nb], 0, 0, 0);
    }

    // epilogue: + (b_ih + b_hh), cast fp16, store
#pragma unroll
    for (int nb = 0; nb < 4; ++nb) {
        const int col = n0 + nb * 16 + c;
        const float bias = bih[col] + bhh[col];
#pragma unroll
        for (int rb = 0; rb < 4; ++rb)
#pragma unroll
            for (int r = 0; r < 4; ++r) {
                const int m = m0 + rb * 16 + q * 4 + r;
                xwb[((size_t)dir * (L_SEQ * NB) + m) * GG + col] =
                    (_Float16)(acc[rb][nb][r] + bias);
            }
    }
}

// ---------------------------------------------------------------------------
// Phase 2: recurrence with 8 independent sync-groups. PLAIN launch (32 blocks
// on 256 CUs are always co-resident). Group = (dir, batch-group of 16 rows);
// 4 blocks/group split 256 h-cols into 64-col slices. bid&7 = group,
// bid>>3 = slice. Block = 256 thr = 4 waves; lane (q,c) holds gates i,f,g,o
// of h-col j for batch rows b0+q*4+r in acc[0..3][r] — no shuffles, c-state
// 4 regs/lane. W_hh slice register-resident (128 VGPRs bf16).
//
// Handshake (this revision — PER-WAVE, no __syncthreads in the loop):
// lstm_recur uses no LDS; waves interact only through L3. Block barriers
// existed only so tid0 could poll/publish for the block — removed:
//  * flags[grp] counts WAVE arrivals: 16 producer waves/group per step.
//  * publish: per-wave s_waitcnt vmcnt(0) (own Hw sc0|sc1 stores acked at the
//    coherent point), then lane 0 of the wave does ONE RELAXED fetch_add
//    (agent-scope atomic executes at the coherent point; compiler emits sc1 —
//    no buffer_wbl2, ordering is by hardware: data acked before flag issued).
//  * acquire: ALL lanes issue the same-address RELAXED atomic load (one
//    coalesced L3 request/wave, uniform branch), spin until cnt >= 16*step,
//    then read Hr via global_load_dwordx4 sc0 sc1 — fresh by construction,
//    no buffer_inv. Buffers are stable when read (double-buffered +
//    count-gated at wave granularity: a wave enters step s+1 — overwriting
//    phase s&1 — only after all 16 waves published s, which is after their
//    phase-s&1 reads), so atomicity is not needed — only freshness.
//  * wave skew (<= 1 step) is absorbed, not serialized: a fast wave starts
//    its next step's xwb prefetch + poll while siblings finish elementwise.
//  * `out` stores stay plain (flushed at kernel end) and sit BELOW the
//    publish; their HBM acks drain under the next step's poll+afrag wait.
// Hbuf+flags zeroed (write-through) by gemm_xwb — prior kernel, same stream.
// ---------------------------------------------------------------------------
__global__ __launch_bounds__(256, 1) void lstm_recur(
    const _Float16* __restrict__ xwb,
    const float* __restrict__ Whh_f,
    const float* __restrict__ Whh_b,
    const float* __restrict__ mask,
    float* __restrict__ out,
    unsigned short* __restrict__ Hbuf,    // [phase][dir][64][256] bf16
    unsigned int* __restrict__ flags)     // [8] stride 32 uints
{
    const int bid = blockIdx.x;           // 0..31
    const int grp = bid & 7;              // dir*4 + gb
    const int dir = grp >> 2;
    const int gb  = grp & 3;
    const int g   = bid >> 3;             // h-col slice 0..3
    unsigned int* cnt = flags + grp * 32;

    const int tid = threadIdx.x;
    const int w   = tid >> 6;
    const int l   = tid & 63;
    const int q   = l >> 4;
    const int c   = l & 15;

    const int b0 = gb * 16;               // group's batch base
    const int j  = 64 * g + 16 * w + c;   // h column [0,256)

    // --- B fragments: W_hh slice, register resident ---
    // gate t: B[k][n=c] = W_hh[t*256 + j][k], lane k-range kt*32+q*8..+7
    const float* __restrict__ Whh = dir ? Whh_b : Whh_f;
    bf16x8 bfrag[4][8];
#pragma unroll
    for (int t = 0; t < 4; ++t) {
        const int gcol = t * HHALF + j;
#pragma unroll
        for (int kt = 0; kt < 8; ++kt) {
            const float4* wp = (const float4*)(Whh + (size_t)gcol * HHALF + kt * 32 + q * 8);
            float4 w0 = wp[0], w1 = wp[1];
            bf16x8 v;
            v[0] = (short)f2bf(w0.x); v[1] = (short)f2bf(w0.y);
            v[2] = (short)f2bf(w0.z); v[3] = (short)f2bf(w0.w);
            v[4] = (short)f2bf(w1.x); v[5] = (short)f2bf(w1.y);
            v[6] = (short)f2bf(w1.z); v[7] = (short)f2bf(w1.w);
            bfrag[t][kt] = v;
        }
    }

    float cstate[4] = {0.f, 0.f, 0.f, 0.f};

    for (int step = 0; step < L_SEQ; ++step) {
        const int tt = dir ? (L_SEQ - 1 - step) : step;

        // ---- prefetch (independent of h): xwb + mask for this step;
        //      loads fly while we spin in the poll below ----
        float xv[4][4];
        const _Float16* xp = xwb + ((size_t)(dir * L_SEQ + tt) * NB + b0 + q * 4) * GG + j;
#pragma unroll
        for (int t = 0; t < 4; ++t)
#pragma unroll
            for (int r = 0; r < 4; ++r)
                xv[t][r] = (float)xp[(size_t)r * GG + t * HHALF];
        float mv[4];
#pragma unroll
        for (int r = 0; r < 4; ++r) mv[r] = mask[tt * NB + b0 + q * 4 + r];

        // ---- per-wave wait: all lanes poll the same address (one coalesced
        //      L3 request per wave), RELAXED — no cache maintenance ----
        {
            const unsigned target = 16u * (unsigned)step;
            while (__hip_atomic_load(cnt, __ATOMIC_RELAXED, __HIP_MEMORY_SCOPE_AGENT) < target) {}
        }

        const unsigned short* __restrict__ Hr =
            Hbuf + (size_t)((step & 1) * 2 + dir) * NB * HHALF;
        unsigned short* __restrict__ Hw =
            Hbuf + (size_t)(((step + 1) & 1) * 2 + dir) * NB * HHALF;

        // ---- A fragments: h rows b0..b0+15, full K=256, coherent loads ----
        bf16x8 afrag[8];
        const unsigned short* hp = Hr + (size_t)(b0 + c) * HHALF;
#pragma unroll
        for (int kt = 0; kt < 8; ++kt) {
            const unsigned short* p = hp + kt * 32 + q * 8;
            asm volatile("global_load_dwordx4 %0, %1, off sc0 sc1"
                         : "=&v"(afrag[kt]) : "v"(p));
        }
        asm volatile("s_waitcnt vmcnt(0)" ::: "memory");
        __builtin_amdgcn_sched_barrier(0);   // rule #18: no use hoists above wait

        // ---- gates = xW (+biases) + h @ W_hh^T ----
        f32x4 acc[4];
#pragma unroll
        for (int t = 0; t < 4; ++t) {
            f32x4 a; a[0] = xv[t][0]; a[1] = xv[t][1]; a[2] = xv[t][2]; a[3] = xv[t][3];
            acc[t] = a;
        }
#pragma unroll
        for (int kt = 0; kt < 8; ++kt)
#pragma unroll
            for (int t = 0; t < 4; ++t)
                acc[t] = __builtin_amdgcn_mfma_f32_16x16x32_bf16(afrag[kt], bfrag[t][kt], acc[t], 0, 0, 0);

        // ---- elementwise: lane holds i,f,g,o for (b0+q*4+r, j) ----
        float hval[4];
#pragma unroll
        for (int r = 0; r < 4; ++r) {
            float gi = acc[0][r], gf = acc[1][r], gg = acc[2][r], go = acc[3][r];
            float cn = fsigmoid(gf) * cstate[r] + fsigmoid(gi) * ftanh(gg);
            float h  = fsigmoid(go) * ftanh(cn);
            float m  = mv[r];
            h  *= m;
            cn *= m;
            cstate[r] = cn;
            hval[r]   = h;
            st_short_wt(Hw + (size_t)(b0 + q * 4 + r) * HHALF + j,
                        (unsigned int)f2bf(h));
        }

        // ---- publish: wait own store acks, ONE relaxed arrival per wave ----
        asm volatile("s_waitcnt vmcnt(0)" ::: "memory");
        __builtin_amdgcn_sched_barrier(0);
        if (l == 0)
            __hip_atomic_fetch_add(cnt, 1u, __ATOMIC_RELAXED, __HIP_MEMORY_SCOPE_AGENT);
        __builtin_amdgcn_sched_barrier(0);   // keep out-stores below the publish

        // ---- out stores: off the critical path (drain under next poll) ----
#pragma unroll
        for (int r = 0; r < 4; ++r) {
            const int b = b0 + q * 4 + r;
            out[((size_t)tt * NB + b) * (2 * HHALF) + dir * HHALF + j] = hval[r];
        }
    }
}

// ---------------------------------------------------------------------------
// Workspace layout:
//   [0, 128 MiB)            xwb   fp16 [2][512][64][1024]
//   [+0,   +128 KiB)        Hbuf  bf16 [2 phases][2 dirs][64][256]
//   [+128K, +1 KiB)         flags u32 [8] stride 32
// Requires ws_size >= 134,349,824 bytes.
// ---------------------------------------------------------------------------
extern "C" void kernel_launch(void* const* d_in, const int* in_sizes, int n_in,
                              void* d_out, int out_size, void* d_ws, size_t ws_size,
                              hipStream_t stream)
{
    (void)in_sizes; (void)n_in; (void)out_size; (void)ws_size;
    const float* x     = (const float*)d_in[0];
    const float* mask  = (const float*)d_in[1];
    const float* Wih_f = (const float*)d_in[2];
    const float* Whh_f = (const float*)d_in[3];
    const float* bih_f = (const float*)d_in[4];
    const float* bhh_f = (const float*)d_in[5];
    const float* Wih_b = (const float*)d_in[6];
    const float* Whh_b = (const float*)d_in[7];
    const float* bih_b = (const float*)d_in[8];
    const float* bhh_b = (const float*)d_in[9];
    float* out = (float*)d_out;

    const size_t xwb_bytes  = (size_t)2 * L_SEQ * NB * GG * sizeof(_Float16);
    const size_t hbuf_bytes = (size_t)2 * 2 * NB * HHALF * sizeof(unsigned short);
    _Float16*       xwb   = (_Float16*)d_ws;
    unsigned short* Hbuf  = (unsigned short*)((char*)d_ws + xwb_bytes);
    unsigned int*   flags = (unsigned int*)((char*)d_ws + xwb_bytes + hbuf_bytes);

    // gemm_xwb also zero-inits Hbuf + flags (33,024 words) from block (0,0,0)
    const int zero_words = (int)((hbuf_bytes + 8 * 32 * sizeof(unsigned int)) / 4);
    hipLaunchKernelGGL(gemm_xwb, dim3(4, 512, 2), dim3(256), 0, stream,
                       x, Wih_f, Wih_b, bih_f, bhh_f, bih_b, bhh_b, xwb,
                       (unsigned int*)Hbuf, zero_words);

    hipLaunchKernelGGL(lstm_recur, dim3(32), dim3(256), 0, stream,
                       xwb, Whh_f, Whh_b, mask, out, Hbuf, flags);
}